// Round 1
// 445.595 us; speedup vs baseline: 1.0410x; 1.0410x over previous
//
#include <hip/hip_runtime.h>
#include <hip/hip_bf16.h>

#define NN 8192
#define DIN 128
#define DOUT 128

typedef __bf16 bf16;
typedef __bf16 bf16x8 __attribute__((ext_vector_type(8)));
typedef float f32x4 __attribute__((ext_vector_type(4)));

// ---- K1: rowsum -> dinv[i] = rsqrt(sum(adj[i,:]) + eps). Pure stream. ----
__global__ __launch_bounds__(256) void k1_rowsum(const float* __restrict__ adj,
                                                 float* __restrict__ dinv) {
    int row = blockIdx.x;
    int t   = threadIdx.x;
    const float4* p = reinterpret_cast<const float4*>(adj + (size_t)row * NN);
    float s = 0.f;
    #pragma unroll
    for (int i = 0; i < 8; ++i) {
        float4 v = p[t + i * 256];
        s += (v.x + v.y) + (v.z + v.w);
    }
    #pragma unroll
    for (int off = 32; off > 0; off >>= 1) s += __shfl_down(s, off, 64);
    __shared__ float r4[4];
    if ((t & 63) == 0) r4[t >> 6] = s;
    __syncthreads();
    if (t == 0) dinv[row] = rsqrtf(((r4[0] + r4[1]) + (r4[2] + r4[3])) + 1e-6f);
}

// ---- K2: z = x @ W^T;  yT[c][j] = bf16(dinv[j] * z[j][c])  (transposed) --
__global__ __launch_bounds__(256) void k2_xwT(const float* __restrict__ x,
                                              const float* __restrict__ W,
                                              const float* __restrict__ dinv,
                                              bf16* __restrict__ yT) {
    __shared__ float Wl[128 * 132];
    __shared__ float xl[32 * 132];
    __shared__ float dl[32];
    int t  = threadIdx.x;
    int i0 = blockIdx.x * 32;
    if (t < 32) dl[t] = dinv[i0 + t];
    #pragma unroll
    for (int s = 0; s < 16; ++s) {
        int i  = t + s * 256;
        int o  = i >> 5;
        int c4 = i & 31;
        *reinterpret_cast<float4*>(&Wl[o * 132 + c4 * 4]) =
            *reinterpret_cast<const float4*>(W + o * 128 + c4 * 4);
    }
    #pragma unroll
    for (int s = 0; s < 4; ++s) {
        int i   = t + s * 256;
        int row = i >> 5;
        int c4  = i & 31;
        *reinterpret_cast<float4*>(&xl[row * 132 + c4 * 4]) =
            *reinterpret_cast<const float4*>(x + (size_t)(i0 + row) * DIN + c4 * 4);
    }
    __syncthreads();
    int o = t & 127;          // output feature (column of z, row of yT)
    int g = t >> 7;           // row group: rows g*16 .. g*16+15
    float acc[16] = {};
    for (int c4 = 0; c4 < 32; ++c4) {
        float4 w4 = *reinterpret_cast<const float4*>(&Wl[o * 132 + c4 * 4]);
        #pragma unroll
        for (int r = 0; r < 16; ++r) {
            float4 h4 = *reinterpret_cast<const float4*>(&xl[(g * 16 + r) * 132 + c4 * 4]);
            acc[r] += h4.x * w4.x + h4.y * w4.y + h4.z * w4.z + h4.w * w4.w;
        }
    }
    bf16x8 o0, o1;
    #pragma unroll
    for (int r = 0; r < 8; ++r) o0[r] = (bf16)(acc[r] * dl[g * 16 + r]);
    #pragma unroll
    for (int r = 0; r < 8; ++r) o1[r] = (bf16)(acc[8 + r] * dl[g * 16 + 8 + r]);
    bf16* dst = yT + (size_t)o * NN + i0 + g * 16;
    *reinterpret_cast<bf16x8*>(dst)     = o0;
    *reinterpret_cast<bf16x8*>(dst + 8) = o1;
}

// ---- K3: partial[split] = dinv[i] * (adj[i, ksplit] @ y[ksplit, :]) ------
// 1 block/CU (grid 256). Each block: 128 rows x K=2048 (4 x 512-k LDS
// restages of yT, register accumulation across chunks). Split-K = 4 via
// PLAIN partial-tile stores (no atomics -> no cross-XCD RMW serialization).
#define KR3 512
#define LDB3 520   // 1040 B row stride: 16B-aligned, slot-disjoint b128 reads

__global__ __launch_bounds__(512, 2) void k3_spmm(const float* __restrict__ adj,
                                                  const bf16* __restrict__ yT,
                                                  const float* __restrict__ dinv,
                                                  float* __restrict__ part) {
    __shared__ bf16 BL[128 * LDB3];   // 130 KB
    int t     = threadIdx.x;
    int split = blockIdx.x & 3;
    int mg    = blockIdx.x >> 2;      // 0..63
    int m0    = mg * 128;
    int kbase = split * 2048;

    int wave = t >> 6, lane = t & 63;
    int mrow = lane & 15, quad = lane >> 4;
    int wm0  = m0 + wave * 16;        // this wave's 16-row strip

    f32x4 acc[8] = {};

    for (int cc = 0; cc < 4; ++cc) {
        int kc = kbase + cc * KR3;
        if (cc) __syncthreads();      // prior chunk's ds_reads done before restage
        for (int i = t; i < 128 * 64; i += 512) {
            int c = i >> 6, ch = i & 63;
            *reinterpret_cast<uint4*>(&BL[c * LDB3 + ch * 8]) =
                *reinterpret_cast<const uint4*>(yT + (size_t)c * NN + kc + ch * 8);
        }
        __syncthreads();

        const float* ap = adj + (size_t)(wm0 + mrow) * NN + kc + quad * 8;
        // 2-deep software pipeline on adj: consume kk, hold kk+1, issue kk+2
        float4 c0 = *(const float4*)(ap);
        float4 c1 = *(const float4*)(ap + 4);
        float4 n0 = *(const float4*)(ap + 32);
        float4 n1 = *(const float4*)(ap + 36);
        #pragma unroll
        for (int kk = 0; kk < KR3 / 32; ++kk) {
            bf16x8 bf[8];
            int boff = kk * 32 + quad * 8;
            #pragma unroll
            for (int nt = 0; nt < 8; ++nt)
                bf[nt] = *reinterpret_cast<const bf16x8*>(&BL[(nt * 16 + mrow) * LDB3 + boff]);
            int pk = (kk < KR3 / 32 - 2) ? (kk + 2) * 32 : 0;   // const-folded
            float4 f0 = *(const float4*)(ap + pk);
            float4 f1 = *(const float4*)(ap + pk + 4);
            bf16x8 af = { (bf16)c0.x, (bf16)c0.y, (bf16)c0.z, (bf16)c0.w,
                          (bf16)c1.x, (bf16)c1.y, (bf16)c1.z, (bf16)c1.w };
            #pragma unroll
            for (int nt = 0; nt < 8; ++nt)
                acc[nt] = __builtin_amdgcn_mfma_f32_16x16x32_bf16(af, bf[nt], acc[nt], 0, 0, 0);
            c0 = n0; c1 = n1; n0 = f0; n1 = f1;
        }
    }

    // epilogue: plain stores of this split's 128x128 tile, scaled by dinv[row]
    f32x4 dv = *reinterpret_cast<const f32x4*>(dinv + wm0 + quad * 4);
    float* pout = part + (size_t)split * (NN * DOUT) + (size_t)wm0 * DOUT;
    #pragma unroll
    for (int nt = 0; nt < 8; ++nt) {
        int col = nt * 16 + mrow;
        #pragma unroll
        for (int r = 0; r < 4; ++r)
            pout[(quad * 4 + r) * DOUT + col] = acc[nt][r] * dv[r];
    }
}

// ---- K4: out = bias + sum over 4 split partials. 20 MB stream. -----------
__global__ __launch_bounds__(256) void k4_reduce(const float* __restrict__ part,
                                                 const float* __restrict__ bias,
                                                 float* __restrict__ out) {
    size_t g = (size_t)blockIdx.x * 256 + threadIdx.x;   // float4 index
    float4 s = *reinterpret_cast<const float4*>(bias + (g & 31) * 4);
    #pragma unroll
    for (int sp = 0; sp < 4; ++sp) {
        float4 p = *reinterpret_cast<const float4*>(part + (size_t)sp * NN * DOUT + g * 4);
        s.x += p.x; s.y += p.y; s.z += p.z; s.w += p.w;
    }
    *reinterpret_cast<float4*>(out + g * 4) = s;
}

extern "C" void kernel_launch(void* const* d_in, const int* in_sizes, int n_in,
                              void* d_out, int out_size, void* d_ws, size_t ws_size,
                              hipStream_t stream) {
    const float* x   = (const float*)d_in[0];
    const float* adj = (const float*)d_in[1];
    const float* W   = (const float*)d_in[2];
    const float* b   = (const float*)d_in[3];
    float* out = (float*)d_out;
    char* ws = (char*)d_ws;
    float* dinv = (float*)ws;                   // 32 KB  @ 0
    bf16*  yT   = (bf16*)(ws + (1u << 20));     // 2 MB   @ 1 MB
    float* part = (float*)(ws + (4u << 20));    // 16 MB  @ 4 MB

    k1_rowsum<<<NN, 256, 0, stream>>>(adj, dinv);
    k2_xwT   <<<NN / 32, 256, 0, stream>>>(x, W, dinv, yT);
    k3_spmm  <<<4 * (NN / 128), 512, 0, stream>>>(adj, yT, dinv, part);
    k4_reduce<<<(NN * DOUT / 4) / 256, 256, 0, stream>>>(part, b, out);
}